// Round 1
// baseline (82.055 us; speedup 1.0000x reference)
//
#include <hip/hip_runtime.h>

// ROI head matcher: for each proposal, argmax-IoU over 128 GT boxes,
// then label assignment + matched GT box gather.
//
// Numerics deliberately replicate the reference op-for-op:
//   x1=max, y1=max, x2=min, y2=min; iw=max(x2-x1,0); ih=max(y2-y1,0);
//   inter=iw*ih; union=(area_g+area_p)-inter; iou=inter/union (IEEE f32 div).
// Strict '>' keeps the FIRST index of the max (jnp.argmax semantics).

#define MAX_GT 128
#define BLOCK 256
#define IOU_THRESHOLD 0.5f
#define LOW_BG_IOU 0.1f

__global__ __launch_bounds__(BLOCK) void roi_match_kernel(
    const float* __restrict__ proposals,   // [N,4]
    const float* __restrict__ gt_boxes,    // [G,4]
    const int*   __restrict__ gt_labels,   // [G] (harness passes integer as int32)
    float* __restrict__ out,               // [N] labels then [N,4] boxes, flat
    int N, int G)
{
    __shared__ float4 s_gt[MAX_GT];
    __shared__ float  s_area[MAX_GT];
    __shared__ float  s_label[MAX_GT];

    for (int g = threadIdx.x; g < G; g += blockDim.x) {
        float4 b = ((const float4*)gt_boxes)[g];
        s_gt[g]   = b;
        s_area[g] = (b.z - b.x) * (b.w - b.y);
        s_label[g] = (float)gt_labels[g];
    }
    __syncthreads();

    int n = blockIdx.x * blockDim.x + threadIdx.x;
    if (n >= N) return;

    float4 p = ((const float4*)proposals)[n];
    float area_p = (p.z - p.x) * (p.w - p.y);

    float best = -1.0f;   // all IoUs >= 0, so g=0 always wins the first compare
    int   bi   = 0;

#pragma unroll 8
    for (int g = 0; g < G; ++g) {
        float4 gb = s_gt[g];
        float x1 = fmaxf(gb.x, p.x);
        float y1 = fmaxf(gb.y, p.y);
        float x2 = fminf(gb.z, p.z);
        float y2 = fminf(gb.w, p.w);
        float iw = fmaxf(x2 - x1, 0.0f);
        float ih = fmaxf(y2 - y1, 0.0f);
        float inter = iw * ih;
        float uni   = (s_area[g] + area_p) - inter;
        float iou   = inter / uni;          // IEEE f32 divide (no fast-math)
        if (iou > best) { best = iou; bi = g; }
    }

    float lab;
    if (best < LOW_BG_IOU)          lab = -1.0f;   // ignored
    else if (best < IOU_THRESHOLD)  lab = 0.0f;    // background
    else                            lab = s_label[bi];

    out[n] = lab;
    // boxes live at out[N + 4*n + k]; N*4 bytes = 800000 is 16B-aligned
    ((float4*)(out + N))[n] = s_gt[bi];
}

extern "C" void kernel_launch(void* const* d_in, const int* in_sizes, int n_in,
                              void* d_out, int out_size, void* d_ws, size_t ws_size,
                              hipStream_t stream) {
    const float* proposals = (const float*)d_in[0];
    const float* gt_boxes  = (const float*)d_in[1];
    const int*   gt_labels = (const int*)d_in[2];
    float* out = (float*)d_out;

    int N = in_sizes[0] / 4;   // 200000
    int G = in_sizes[1] / 4;   // 128

    int blocks = (N + BLOCK - 1) / BLOCK;
    roi_match_kernel<<<blocks, BLOCK, 0, stream>>>(proposals, gt_boxes, gt_labels,
                                                   out, N, G);
}

// Round 2
// 77.480 us; speedup vs baseline: 1.0590x; 1.0590x over previous
//
#include <hip/hip_runtime.h>

// ROI head matcher: per proposal, argmax-IoU over 128 GT boxes, then label
// assignment + matched GT box gather.
//
// R2: per-iteration IEEE divide replaced by an EXACT cross-multiplication
// comparison (Dekker two-product + two-term compare):
//   inter_g/uni_g > inter_b/uni_b  <=>  inter_g*uni_b > inter_b*uni_g
// Products represented exactly as p+e (e = fmaf(a,b,-p)); comparison
//   (p1+e1) > (p2+e2)  <=>  (p1-p2) > (e2-e1)
// is exact except at true ties, where "keep first" matches jnp.argmax.
// When the reference's f32 quotients differ, monotone rounding guarantees
// the exact comparison agrees. One IEEE divide remains in the epilogue so
// the threshold tests see the bit-identical max IoU.

#define MAX_GT 128
#define BLOCK 256
#define IOU_THRESHOLD 0.5f
#define LOW_BG_IOU 0.1f

__global__ __launch_bounds__(BLOCK) void roi_match_kernel(
    const float* __restrict__ proposals,   // [N,4]
    const float* __restrict__ gt_boxes,    // [G,4]
    const int*   __restrict__ gt_labels,   // [G]
    float* __restrict__ out,               // [N] labels then [N,4] boxes
    int N, int G)
{
#pragma clang fp contract(off)
    __shared__ float4 s_gt[MAX_GT];
    __shared__ float  s_area[MAX_GT];
    __shared__ float  s_label[MAX_GT];

    for (int g = threadIdx.x; g < G; g += blockDim.x) {
        float4 b = ((const float4*)gt_boxes)[g];
        s_gt[g]    = b;
        s_area[g]  = (b.z - b.x) * (b.w - b.y);
        s_label[g] = (float)gt_labels[g];
    }
    __syncthreads();

    int n = blockIdx.x * blockDim.x + threadIdx.x;
    if (n >= N) return;

    float4 p = ((const float4*)proposals)[n];
    float area_p = (p.z - p.x) * (p.w - p.y);

    // g = 0 initializes the running best (argmax first-index semantics).
    int   bi = 0;
    float inter_b, uni_b;
    {
        float4 gb = s_gt[0];
        float x1 = fmaxf(gb.x, p.x);
        float y1 = fmaxf(gb.y, p.y);
        float x2 = fminf(gb.z, p.z);
        float y2 = fminf(gb.w, p.w);
        float iw = fmaxf(x2 - x1, 0.0f);
        float ih = fmaxf(y2 - y1, 0.0f);
        inter_b = iw * ih;
        uni_b   = (s_area[0] + area_p) - inter_b;
    }

#pragma unroll 8
    for (int g = 1; g < G; ++g) {
        float4 gb = s_gt[g];
        float x1 = fmaxf(gb.x, p.x);
        float y1 = fmaxf(gb.y, p.y);
        float x2 = fminf(gb.z, p.z);
        float y2 = fminf(gb.w, p.w);
        float iw = fmaxf(x2 - x1, 0.0f);
        float ih = fmaxf(y2 - y1, 0.0f);
        float inter = iw * ih;
        float uni   = (s_area[g] + area_p) - inter;

        // exact products: P1 = inter*uni_b, P2 = inter_b*uni
        float p1 = inter * uni_b;
        float e1 = fmaf(inter, uni_b, -p1);
        float p2 = inter_b * uni;
        float e2 = fmaf(inter_b, uni, -p2);
        bool gt = (p1 - p2) > (e2 - e1);   // exact P1 > P2

        bi      = gt ? g     : bi;
        inter_b = gt ? inter : inter_b;
        uni_b   = gt ? uni   : uni_b;
    }

    float best = inter_b / uni_b;   // IEEE div, bit-identical to reference max

    float lab;
    if (best < LOW_BG_IOU)          lab = -1.0f;       // ignored
    else if (best < IOU_THRESHOLD)  lab = 0.0f;        // background
    else                            lab = s_label[bi];

    out[n] = lab;
    ((float4*)(out + N))[n] = s_gt[bi];   // N*4 B = 800000, 16B-aligned
}

extern "C" void kernel_launch(void* const* d_in, const int* in_sizes, int n_in,
                              void* d_out, int out_size, void* d_ws, size_t ws_size,
                              hipStream_t stream) {
    const float* proposals = (const float*)d_in[0];
    const float* gt_boxes  = (const float*)d_in[1];
    const int*   gt_labels = (const int*)d_in[2];
    float* out = (float*)d_out;

    int N = in_sizes[0] / 4;   // 200000
    int G = in_sizes[1] / 4;   // 128

    int blocks = (N + BLOCK - 1) / BLOCK;
    roi_match_kernel<<<blocks, BLOCK, 0, stream>>>(proposals, gt_boxes, gt_labels,
                                                   out, N, G);
}